// Round 5
// baseline (47.994 us; speedup 1.0000x reference)
//
#include <hip/hip_runtime.h>
#include <math.h>

namespace {

constexpr float kAlpha   = 0.75f;
constexpr int   kNumNeg  = 10000;
constexpr int   kNumHard = 100;
constexpr int   kRatio   = 100;
constexpr int   kB       = 8;
constexpr int   kN       = 64 * 128 * 128;        // 1048576
constexpr int   kSlices  = 24;                    // pos blocks per batch
constexpr int   kPosBlocks    = kB * kSlices;     // 192
constexpr int   kGatherBlocks = 56;
constexpr int   kGrid    = kPosBlocks + kGatherBlocks + kB;   // 256 == #CUs
constexpr int   kTpb     = 1024;
constexpr int   kWaves   = kTpb / 64;             // 16
constexpr int   kVPer    = (kNumNeg + kTpb - 1) / kTpb;  // 10
constexpr unsigned kSentinel = 0xFFFFFFFFu;
constexpr unsigned kMagic    = 0x13579BDFu;

// workspace layout, offsets in 4-byte words
constexpr int oPartials    = 0;      // 192*2 floats
constexpr int oBatchLoss   = 512;    // 8 floats
constexpr int oPosFlags    = 1024;   // 192 u32
constexpr int oGatherFlags = 1280;   // 56 u32
constexpr int oLossFlags   = 1408;   // 8 u32
constexpr int oGvals       = 1536;   // 80000 u32

__device__ __forceinline__ float loss_at(float pred, float target, float mask) {
    float prob = 1.0f / (1.0f + expf(-pred));
    prob = fminf(fmaxf(prob, 1.0e-4f), 1.0f - 1.0e-4f);
    bool pos = (target == 1.0f);
    float alpha_f = pos ? kAlpha : (1.0f - kAlpha);
    float pt = pos ? (1.0f - prob) : prob;
    float focal_w = alpha_f * pt * pt;
    float bce = fmaxf(pred, 0.0f) - pred * target + log1pf(expf(-fabsf(pred)));
    float loss = (mask == 0.0f) ? focal_w * bce : 0.0f;
    if (pos && prob < 0.8f) loss *= 4.0f;
    return loss;
}

__device__ __forceinline__ unsigned flag_load(const unsigned* p) {
    return __hip_atomic_load(p, __ATOMIC_ACQUIRE, __HIP_MEMORY_SCOPE_AGENT);
}
__device__ __forceinline__ void flag_store(unsigned* p, unsigned v) {
    __hip_atomic_store(p, v, __ATOMIC_RELEASE, __HIP_MEMORY_SCOPE_AGENT);
}

// One kernel, 256 co-resident blocks (deadlock-free: grid == CU count,
// __launch_bounds__(1024,4) guarantees 1 block/CU schedulable).
__global__ void __launch_bounds__(kTpb, 4) fused_kernel(
        const float* __restrict__ pred, const float* __restrict__ target,
        const float* __restrict__ mask, const int* __restrict__ neg_idx,
        unsigned* __restrict__ ws, float* __restrict__ out) {
    const int blk = blockIdx.x;
    const int tid = threadIdx.x;
    const int wave = tid >> 6, lane = tid & 63;
    float* wsf = (float*)ws;

    if (blk < kPosBlocks) {
        // ---- pos-stream block: batch b, slice of the target stream ----
        const int b = blk & 7;
        const int slice = blk >> 3;                       // [0,24)
        const size_t base = (size_t)b * kN;
        const float4* t4 = (const float4*)(target + base);
        const int nvec = kN / 4;

        float cnt = 0.0f, psum = 0.0f;
        for (int i = slice * kTpb + tid; i < nvec; i += kSlices * kTpb) {
            float4 tv = t4[i];
            float tvv[4] = {tv.x, tv.y, tv.z, tv.w};
            #pragma unroll
            for (int c = 0; c < 4; ++c) {
                if (tvv[c] == 1.0f) {
                    int gi = i * 4 + c;
                    cnt += 1.0f;
                    psum += loss_at(pred[base + gi], 1.0f, mask[base + gi]);
                }
            }
        }
        #pragma unroll
        for (int off = 32; off > 0; off >>= 1) {
            cnt  += __shfl_down(cnt, off);
            psum += __shfl_down(psum, off);
        }
        __shared__ float sc[kWaves], sp[kWaves];
        if (lane == 0) { sc[wave] = cnt; sp[wave] = psum; }
        __syncthreads();
        if (tid == 0) {
            float c = 0.0f, p = 0.0f;
            for (int w = 0; w < kWaves; ++w) { c += sc[w]; p += sp[w]; }
            wsf[oPartials + 2 * blk]     = c;
            wsf[oPartials + 2 * blk + 1] = p;
            __threadfence();
            flag_store(&ws[oPosFlags + blk], kMagic);
        }
    } else if (blk < kPosBlocks + kGatherBlocks) {
        // ---- gather block: random candidate losses ----
        const int g = blk - kPosBlocks;
        for (int t = g * kTpb + tid; t < kB * kNumNeg; t += kGatherBlocks * kTpb) {
            const int b2 = t / kNumNeg;
            const int j  = t - b2 * kNumNeg;
            const size_t base = (size_t)b2 * kN;
            const int gi = neg_idx[(size_t)b2 * kNumNeg + j];
            const float tg = target[base + gi];
            unsigned outv;
            if (tg == 1.0f) {
                outv = kSentinel;
            } else {
                float v = loss_at(pred[base + gi], tg, mask[base + gi]);
                outv = __float_as_uint(v);                // v >= 0, finite
            }
            ws[oGvals + t] = outv;
        }
        __syncthreads();
        if (tid == 0) {
            __threadfence();
            flag_store(&ws[oGatherFlags + g], kMagic);
        }
    } else {
        // ---- select block: exact top-k sum for batch b ----
        const int b = blk - (kPosBlocks + kGatherBlocks);
        __shared__ unsigned whist[kWaves][256];           // 16 KB
        __shared__ unsigned hist_total[256], sfx[256];
        __shared__ float r0[kWaves], r1[kWaves], red[kWaves];
        __shared__ float sh_np, sh_ps;
        __shared__ unsigned sh_krem, sh_prefix;
        __shared__ int sh_done;

        for (int i = tid; i < kWaves * 256; i += kTpb)
            ((unsigned*)whist)[i] = 0u;
        __syncthreads();

        // wait for all gather blocks (they finish early)
        if (tid < kGatherBlocks) {
            while (flag_load(&ws[oGatherFlags + tid]) != kMagic)
                __builtin_amdgcn_s_sleep(8);
        }
        __syncthreads();

        // load candidates to registers; valid count/sum; pass-0 histogram.
        // This overlaps the still-running pos stream.
        unsigned vreg[kVPer];
        float mcnt = 0.0f, msum = 0.0f;
        #pragma unroll
        for (int it = 0; it < kVPer; ++it) {
            const int j = tid + it * kTpb;
            unsigned v = kSentinel;
            if (j < kNumNeg) v = ws[oGvals + b * kNumNeg + j];
            vreg[it] = v;
            if (v != kSentinel) {
                mcnt += 1.0f;
                msum += __uint_as_float(v);
                atomicAdd(&whist[wave][v >> 24], 1u);
            }
        }
        #pragma unroll
        for (int off = 32; off > 0; off >>= 1) {
            mcnt += __shfl_down(mcnt, off);
            msum += __shfl_down(msum, off);
        }
        if (lane == 0) { r0[wave] = mcnt; r1[wave] = msum; }

        // wait for this batch's 24 pos partials (lane-local flag+data)
        float c = 0.0f, p = 0.0f;
        if (tid < kSlices) {
            const int pb = tid * 8 + b;                   // pos block index
            while (flag_load(&ws[oPosFlags + pb]) != kMagic)
                __builtin_amdgcn_s_sleep(8);
            c = wsf[oPartials + 2 * pb];
            p = wsf[oPartials + 2 * pb + 1];
        }
        #pragma unroll
        for (int off = 32; off > 0; off >>= 1) {
            c += __shfl_down(c, off);
            p += __shfl_down(p, off);
        }
        __syncthreads();          // whist + r0/r1 ready

        float my_loss = 0.0f;
        if (tid == 0) {
            float a0 = 0.0f, a1 = 0.0f;
            for (int w = 0; w < kWaves; ++w) { a0 += r0[w]; a1 += r1[w]; }
            sh_np = c; sh_ps = p;
            const int num_pos = (int)c;
            const int m = (int)a0;
            const int k = (num_pos > 0) ? min(kRatio * num_pos, kNumNeg) : kNumHard;
            if (k >= m) {
                my_loss = (p + a1) / fmaxf(c, 1.0f);
                sh_done = 1;
            } else {
                sh_done = 0;
                sh_krem = (unsigned)k;
                sh_prefix = 0u;
            }
        }
        __syncthreads();

        if (!sh_done) {
            #pragma unroll
            for (int pass = 0; pass < 4; ++pass) {
                const int shift = 24 - 8 * pass;
                if (pass > 0) {
                    for (int i = tid; i < kWaves * 256; i += kTpb)
                        ((unsigned*)whist)[i] = 0u;
                    __syncthreads();
                    const unsigned pmask = 0xFFFFFFFFu << (shift + 8);
                    const unsigned pval = sh_prefix;
                    #pragma unroll
                    for (int it = 0; it < kVPer; ++it) {
                        unsigned v = vreg[it];
                        if (v != kSentinel && (v & pmask) == pval)
                            atomicAdd(&whist[wave][(v >> shift) & 255u], 1u);
                    }
                }
                __syncthreads();
                if (tid < 256) {
                    unsigned h = 0;
                    #pragma unroll
                    for (int w = 0; w < kWaves; ++w) h += whist[w][tid];
                    hist_total[tid] = h;
                }
                __syncthreads();
                if (wave == 0) {   // suffix-inclusive sums
                    unsigned v0 = hist_total[255 - (4 * lane + 0)];
                    unsigned v1 = hist_total[255 - (4 * lane + 1)];
                    unsigned v2 = hist_total[255 - (4 * lane + 2)];
                    unsigned v3 = hist_total[255 - (4 * lane + 3)];
                    unsigned p0 = v0, p1 = p0 + v1, p2 = p1 + v2, p3 = p2 + v3;
                    unsigned acc = p3;
                    #pragma unroll
                    for (int off = 1; off < 64; off <<= 1) {
                        unsigned y = __shfl_up(acc, off);
                        if (lane >= off) acc += y;
                    }
                    unsigned excl = acc - p3;
                    sfx[255 - (4 * lane + 0)] = excl + p0;
                    sfx[255 - (4 * lane + 1)] = excl + p1;
                    sfx[255 - (4 * lane + 2)] = excl + p2;
                    sfx[255 - (4 * lane + 3)] = excl + p3;
                }
                __syncthreads();
                const unsigned krem = sh_krem;            // snapshot
                __syncthreads();
                if (tid < 256) {
                    unsigned si = sfx[tid];
                    bool sel = (si >= krem) && (tid == 255 || sfx[tid + 1] < krem);
                    if (sel) {
                        sh_krem = krem - (si - hist_total[tid]);
                        sh_prefix |= (unsigned)tid << shift;
                    }
                }
                __syncthreads();
            }

            const unsigned tbits = sh_prefix;
            float gsum = 0.0f;
            #pragma unroll
            for (int it = 0; it < kVPer; ++it) {
                unsigned v = vreg[it];
                if (v != kSentinel && v > tbits) gsum += __uint_as_float(v);
            }
            #pragma unroll
            for (int off = 32; off > 0; off >>= 1) gsum += __shfl_down(gsum, off);
            if (lane == 0) red[wave] = gsum;
            __syncthreads();
            if (tid == 0) {
                float sum_gt = 0.0f;
                for (int w = 0; w < kWaves; ++w) sum_gt += red[w];
                const float tval = __uint_as_float(sh_prefix);
                const float neg_sum = sum_gt + (float)sh_krem * tval;
                my_loss = (sh_ps + neg_sum) / fmaxf(sh_np, 1.0f);
            }
        }

        if (tid == 0) {
            wsf[oBatchLoss + b] = my_loss;
            __threadfence();
            flag_store(&ws[oLossFlags + b], kMagic);
            if (b == 0) {   // finalize: fixed-order sum over the 8 batches
                float s = 0.0f;
                for (int i = 0; i < kB; ++i) {
                    while (flag_load(&ws[oLossFlags + i]) != kMagic)
                        __builtin_amdgcn_s_sleep(8);
                    s += wsf[oBatchLoss + i];
                }
                out[0] = s / (float)kB;
            }
        }
    }
}

} // namespace

extern "C" void kernel_launch(void* const* d_in, const int* in_sizes, int n_in,
                              void* d_out, int out_size, void* d_ws, size_t ws_size,
                              hipStream_t stream) {
    const float* pred   = (const float*)d_in[0];
    const float* target = (const float*)d_in[1];
    const float* mask   = (const float*)d_in[2];
    const int*   negidx = (const int*)d_in[3];
    unsigned* ws = (unsigned*)d_ws;
    float* out = (float*)d_out;

    // clear flag words (oPosFlags..oGvals) each call: handshake is re-entrant
    hipMemsetAsync((char*)d_ws + oPosFlags * 4, 0, (oGvals - oPosFlags) * 4, stream);
    fused_kernel<<<dim3(kGrid), dim3(kTpb), 0, stream>>>(pred, target, mask,
                                                         negidx, ws, out);
}

// Round 6
// 28.991 us; speedup vs baseline: 1.6555x; 1.6555x over previous
//
#include <hip/hip_runtime.h>
#include <math.h>

namespace {

constexpr float kAlpha   = 0.75f;
constexpr int   kNumNeg  = 10000;
constexpr int   kNumHard = 100;
constexpr int   kRatio   = 100;
constexpr int   kB       = 8;
constexpr int   kN       = 64 * 128 * 128;   // 1048576
constexpr int   kTpb1    = 256;
constexpr int   kGatherBlocks = (kB * kNumNeg + kTpb1 - 1) / kTpb1;   // 313
constexpr int   kSlices  = 256;                       // stream blocks per batch
constexpr int   kPosBlocks = kB * kSlices;            // 2048
constexpr int   kTpbSel  = 1024;
constexpr int   kWavesSel = kTpbSel / 64;             // 16
constexpr int   kVPerThread = (kNumNeg + kTpbSel - 1) / kTpbSel;  // 10
constexpr unsigned kSentinel = 0xFFFFFFFFu;

__device__ __forceinline__ float loss_at(float pred, float target, float mask) {
    float prob = 1.0f / (1.0f + expf(-pred));
    prob = fminf(fmaxf(prob, 1.0e-4f), 1.0f - 1.0e-4f);
    bool pos = (target == 1.0f);
    float alpha_f = pos ? kAlpha : (1.0f - kAlpha);
    float pt = pos ? (1.0f - prob) : prob;
    float focal_w = alpha_f * pt * pt;
    float bce = fmaxf(pred, 0.0f) - pred * target + log1pf(expf(-fabsf(pred)));
    float loss = (mask == 0.0f) ? focal_w * bce : 0.0f;
    if (pos && prob < 0.8f) loss *= 4.0f;
    return loss;
}

// Stage 1: gather blocks FIRST (long-latency random misses start early,
// overlap under the stream), then 2048 stream blocks with 4-deep MLP.
__global__ void __launch_bounds__(kTpb1) stage1_kernel(
        const float* __restrict__ pred, const float* __restrict__ target,
        const float* __restrict__ mask, const int* __restrict__ neg_idx,
        float* __restrict__ partials, unsigned* __restrict__ gvals,
        unsigned* __restrict__ counter) {
    const int blk = blockIdx.x;
    if (blk == 0 && threadIdx.x == 0) *counter = 0u;  // visible at kernel end

    if (blk < kGatherBlocks) {
        // ---- gather: one element per thread ----
        const int t = blk * kTpb1 + threadIdx.x;
        if (t < kB * kNumNeg) {
            const int b = t / kNumNeg;
            const int j = t - b * kNumNeg;
            const size_t base = (size_t)b * kN;
            const int gi = neg_idx[(size_t)b * kNumNeg + j];
            const float tg = target[base + gi];
            unsigned outv;
            if (tg == 1.0f) {
                outv = kSentinel;
            } else {
                float v = loss_at(pred[base + gi], tg, mask[base + gi]);
                outv = __float_as_uint(v);            // v >= 0, finite
            }
            gvals[(size_t)b * kNumNeg + j] = outv;
        }
        return;
    }

    // ---- stream: batch b, slice of 65536 threads; 4 independent float4s ----
    const int pb = blk - kGatherBlocks;
    const int b = pb >> 8;                            // 256 slices per batch
    const int slice = pb & 255;
    const size_t base = (size_t)b * kN;
    const float4* t4 = (const float4*)(target + base);
    const int tb = slice * kTpb1 + threadIdx.x;       // [0, 65536)
    constexpr int kStride = kSlices * kTpb1;          // 65536
    // nvec = kN/4 = 262144 = 4 * kStride exactly
    float4 v0 = t4[tb];
    float4 v1 = t4[tb + kStride];
    float4 v2 = t4[tb + 2 * kStride];
    float4 v3 = t4[tb + 3 * kStride];

    float cnt = 0.0f, psum = 0.0f;
    const float4 vv[4] = {v0, v1, v2, v3};
    #pragma unroll
    for (int it = 0; it < 4; ++it) {
        const int i = tb + it * kStride;
        float tvv[4] = {vv[it].x, vv[it].y, vv[it].z, vv[it].w};
        #pragma unroll
        for (int c = 0; c < 4; ++c) {
            if (tvv[c] == 1.0f) {
                int gi = i * 4 + c;
                cnt += 1.0f;
                psum += loss_at(pred[base + gi], 1.0f, mask[base + gi]);
            }
        }
    }
    #pragma unroll
    for (int off = 32; off > 0; off >>= 1) {
        cnt  += __shfl_down(cnt, off);
        psum += __shfl_down(psum, off);
    }
    __shared__ float sc[kTpb1 / 64], sp[kTpb1 / 64];
    const int wave = threadIdx.x / 64, lane = threadIdx.x % 64;
    if (lane == 0) { sc[wave] = cnt; sp[wave] = psum; }
    __syncthreads();
    if (threadIdx.x == 0) {
        float c = 0.0f, p = 0.0f;
        for (int w = 0; w < kTpb1 / 64; ++w) { c += sc[w]; p += sp[w]; }
        float* slot = partials + ((size_t)b * kSlices + slice) * 2;
        slot[0] = c; slot[1] = p;
    }
}

// Stage 2: one block per batch. Exact top-k sum via 4-pass radix select.
// Candidates in registers; last-arriving block computes the final mean.
__global__ void __launch_bounds__(kTpbSel) select_kernel(
        const unsigned* __restrict__ gvals, const float* __restrict__ partials,
        float* __restrict__ batch_loss, unsigned* __restrict__ counter,
        float* __restrict__ out) {
    __shared__ unsigned whist[kWavesSel][256];        // 16 KB
    __shared__ unsigned hist_total[256];
    __shared__ unsigned sfx[256];
    __shared__ float r0[kWavesSel], r1[kWavesSel], r2[kWavesSel], r3[kWavesSel];
    __shared__ float red[kWavesSel];
    __shared__ float sh_np, sh_ps;
    __shared__ unsigned sh_krem, sh_prefix;
    __shared__ int sh_done;

    const int b = blockIdx.x;
    const int tid = threadIdx.x;
    const int wave = tid >> 6, lane = tid & 63;

    for (int i = tid; i < kWavesSel * 256; i += kTpbSel)
        ((unsigned*)whist)[i] = 0u;
    __syncthreads();

    // load candidates into registers; count/sum valid; pass-0 histogram
    unsigned vreg[kVPerThread];
    float mcnt = 0.0f, msum = 0.0f;
    #pragma unroll
    for (int it = 0; it < kVPerThread; ++it) {
        const int j = tid + it * kTpbSel;
        unsigned v = kSentinel;
        if (j < kNumNeg) v = gvals[(size_t)b * kNumNeg + j];
        vreg[it] = v;
        if (v != kSentinel) {
            mcnt += 1.0f;
            msum += __uint_as_float(v);
            atomicAdd(&whist[wave][v >> 24], 1u);     // v>=0 → bucket <128
        }
    }
    float c = 0.0f, p = 0.0f;
    if (tid < kSlices) {                              // 256 slots per batch
        const float* slot = partials + ((size_t)b * kSlices + tid) * 2;
        c = slot[0]; p = slot[1];
    }
    #pragma unroll
    for (int off = 32; off > 0; off >>= 1) {
        mcnt += __shfl_down(mcnt, off);
        msum += __shfl_down(msum, off);
        c    += __shfl_down(c, off);
        p    += __shfl_down(p, off);
    }
    if (lane == 0) { r0[wave] = mcnt; r1[wave] = msum; r2[wave] = c; r3[wave] = p; }
    __syncthreads();
    float my_loss = 0.0f;          // only thread 0's value is used
    if (tid == 0) {
        float a0 = 0, a1 = 0, a2 = 0, a3 = 0;
        for (int w = 0; w < kWavesSel; ++w) { a0 += r0[w]; a1 += r1[w]; a2 += r2[w]; a3 += r3[w]; }
        sh_np = a2; sh_ps = a3;
        const int num_pos = (int)a2;
        const int m = (int)a0;
        const int k = (num_pos > 0) ? min(kRatio * num_pos, kNumNeg) : kNumHard;
        if (k >= m) {
            my_loss = (a3 + a1) / fmaxf(a2, 1.0f);
            sh_done = 1;
        } else {
            sh_done = 0;
            sh_krem = (unsigned)k;
            sh_prefix = 0u;
        }
    }
    __syncthreads();

    if (!sh_done) {
        #pragma unroll
        for (int pass = 0; pass < 4; ++pass) {
            const int shift = 24 - 8 * pass;
            if (pass > 0) {
                for (int i = tid; i < kWavesSel * 256; i += kTpbSel)
                    ((unsigned*)whist)[i] = 0u;
                __syncthreads();
                const unsigned pmask = 0xFFFFFFFFu << (shift + 8);
                const unsigned pval = sh_prefix;
                #pragma unroll
                for (int it = 0; it < kVPerThread; ++it) {
                    unsigned v = vreg[it];
                    if (v != kSentinel && (v & pmask) == pval)
                        atomicAdd(&whist[wave][(v >> shift) & 255u], 1u);
                }
            }
            __syncthreads();
            if (tid < 256) {
                unsigned h = 0;
                #pragma unroll
                for (int w = 0; w < kWavesSel; ++w) h += whist[w][tid];
                hist_total[tid] = h;
            }
            __syncthreads();
            if (wave == 0) {       // suffix-inclusive sums over buckets
                unsigned v0 = hist_total[255 - (4 * lane + 0)];
                unsigned v1 = hist_total[255 - (4 * lane + 1)];
                unsigned v2 = hist_total[255 - (4 * lane + 2)];
                unsigned v3 = hist_total[255 - (4 * lane + 3)];
                unsigned p0 = v0, p1 = p0 + v1, p2 = p1 + v2, p3 = p2 + v3;
                unsigned acc = p3;
                #pragma unroll
                for (int off = 1; off < 64; off <<= 1) {
                    unsigned y = __shfl_up(acc, off);
                    if (lane >= off) acc += y;
                }
                unsigned excl = acc - p3;
                sfx[255 - (4 * lane + 0)] = excl + p0;
                sfx[255 - (4 * lane + 1)] = excl + p1;
                sfx[255 - (4 * lane + 2)] = excl + p2;
                sfx[255 - (4 * lane + 3)] = excl + p3;
            }
            __syncthreads();
            const unsigned krem = sh_krem;            // snapshot before rewrite
            __syncthreads();
            if (tid < 256) {
                unsigned si = sfx[tid];
                bool sel = (si >= krem) && (tid == 255 || sfx[tid + 1] < krem);
                if (sel) {
                    sh_krem = krem - (si - hist_total[tid]);
                    sh_prefix |= (unsigned)tid << shift;
                }
            }
            __syncthreads();
        }

        const unsigned tbits = sh_prefix;
        float gsum = 0.0f;
        #pragma unroll
        for (int it = 0; it < kVPerThread; ++it) {
            unsigned v = vreg[it];
            if (v != kSentinel && v > tbits) gsum += __uint_as_float(v);
        }
        #pragma unroll
        for (int off = 32; off > 0; off >>= 1) gsum += __shfl_down(gsum, off);
        if (lane == 0) red[wave] = gsum;
        __syncthreads();
        if (tid == 0) {
            float sum_gt = 0.0f;
            for (int w = 0; w < kWavesSel; ++w) sum_gt += red[w];
            const float tval = __uint_as_float(sh_prefix);
            const float neg_sum = sum_gt + (float)sh_krem * tval;
            my_loss = (sh_ps + neg_sum) / fmaxf(sh_np, 1.0f);
        }
    }

    // fused finalize: last-arriving block computes the mean
    if (tid == 0) {
        __hip_atomic_store(&batch_loss[b], my_loss, __ATOMIC_RELEASE,
                           __HIP_MEMORY_SCOPE_AGENT);
        unsigned old = __hip_atomic_fetch_add(counter, 1u, __ATOMIC_ACQ_REL,
                                              __HIP_MEMORY_SCOPE_AGENT);
        if (old == (unsigned)(kB - 1)) {
            float s = 0.0f;
            for (int i = 0; i < kB; ++i)
                s += __hip_atomic_load(&batch_loss[i], __ATOMIC_ACQUIRE,
                                       __HIP_MEMORY_SCOPE_AGENT);
            out[0] = s / (float)kB;
        }
    }
}

} // namespace

extern "C" void kernel_launch(void* const* d_in, const int* in_sizes, int n_in,
                              void* d_out, int out_size, void* d_ws, size_t ws_size,
                              hipStream_t stream) {
    const float* pred   = (const float*)d_in[0];
    const float* target = (const float*)d_in[1];
    const float* mask   = (const float*)d_in[2];
    const int*   negidx = (const int*)d_in[3];
    float* ws = (float*)d_ws;
    float*    partials   = ws;                         // 2048*2 floats
    float*    batch_loss = ws + 4096;                  // 8 floats
    unsigned* counter    = (unsigned*)(ws + 4104);     // 1 uint
    unsigned* gvals      = (unsigned*)(ws + 4112);     // 80000 uints
    float* out = (float*)d_out;

    stage1_kernel<<<dim3(kGatherBlocks + kPosBlocks), dim3(kTpb1), 0, stream>>>(
        pred, target, mask, negidx, partials, gvals, counter);
    select_kernel<<<dim3(kB), dim3(kTpbSel), 0, stream>>>(
        gvals, partials, batch_loss, counter, out);
}